// Round 7
// baseline (100.860 us; speedup 1.0000x reference)
//
#include <hip/hip_runtime.h>
#include <hip/hip_bf16.h>
#include <math.h>

// Problem: N=50000 nodes, E=800000 edges, D=G=128.
// out[v,:] = elu( sum_{e: dst(e)=v} softmax_e(leaky(pd[dst]+ps[src]+b)) * hv[src(e),:] )
// pd[v] = nf[v]·W_edge[0:D] (+ b_edge), ps[v] = nf[v]·W_edge[D:2D]
// hv = leaky_relu(nf @ W_node + b_node) via bf16 MFMA, stored as packed bf16 pairs.
// Edge ordering via 2-level binned multisplit (64-dst buckets, fixed CAP slots);
// requires nN <= 65536 (src/dst packed in 16 bits) — holds for this problem.

#define BK_SHIFT 6
#define BK_CAP 2048
#define BIN_CHUNK 4096

using bf16x8 = __attribute__((ext_vector_type(8))) __bf16;
using f32x4 = __attribute__((ext_vector_type(4))) float;

static __device__ __forceinline__ unsigned pack_bf16(float x0, float x1) {
  unsigned u0 = (unsigned)__bfloat16_as_ushort(__float2bfloat16(x0));
  unsigned u1 = (unsigned)__bfloat16_as_ushort(__float2bfloat16(x1));
  return u0 | (u1 << 16);
}

// ---- one-time: convert Wn (128x128 f32) to bf16, pre-swizzled into B-fragment order.
// Also zeroes bcnt (replaces hipMemsetAsync — saves one in-graph fill dispatch).
__global__ void wconv_kernel(const float* __restrict__ Wn, ushort* __restrict__ wsw,
                             int* __restrict__ bcnt, int nB) {
  int i = blockIdx.x * 256 + threadIdx.x;  // 0..16383
  if (i < nB) bcnt[i] = 0;
  int j = i & 7, l = (i >> 3) & 63, ct = (i >> 9) & 7, kstep = i >> 12;
  int k = kstep * 32 + ((l >> 4) << 3) + j;
  int c = ct * 16 + (l & 15);
  wsw[i] = __bfloat16_as_ushort(__float2bfloat16(Wn[k * 128 + c]));
}

// ---------------- fused: hv MFMA GEMM (bf16) + per-node edge scalars ----------------
__global__ __launch_bounds__(256) void hv_mfma_kernel(
    const float* __restrict__ nf, const ushort* __restrict__ wsw,
    const float* __restrict__ bn, const float* __restrict__ We,
    const float* __restrict__ be, unsigned* __restrict__ hv2,
    float* __restrict__ pd, float* __restrict__ ps, int nN) {
  __shared__ unsigned Atile[64 * 64];  // 64 rows x 256B of bf16, XOR-swizzled 16B slots
  int row0 = blockIdx.x * 64;
  int t = threadIdx.x;
#pragma unroll
  for (int ss = 0; ss < 4; ++ss) {
    int s = t + ss * 256;
    int r = s >> 4, sl = s & 15;
    int gr = row0 + r;
    float4 f0 = make_float4(0.f, 0.f, 0.f, 0.f), f1 = f0;
    if (gr < nN) {
      const float4* p = reinterpret_cast<const float4*>(nf + (size_t)gr * 128 + sl * 8);
      f0 = p[0];
      f1 = p[1];
    }
    uint4 pk;
    pk.x = pack_bf16(f0.x, f0.y);
    pk.y = pack_bf16(f0.z, f0.w);
    pk.z = pack_bf16(f1.x, f1.y);
    pk.w = pack_bf16(f1.z, f1.w);
    int byte = r * 256 + ((sl * 16) ^ ((r & 7) << 4));  // T2 swizzle vs 16-way conflict
    *reinterpret_cast<uint4*>(reinterpret_cast<char*>(Atile) + byte) = pk;
  }
  __syncthreads();
  int lane = t & 63, w = t >> 6;
  // edge-projection scalars (fp32, reads nf from global -> L1/L2-hot after staging)
  float we0 = We[lane], we1 = We[64 + lane], we2 = We[128 + lane], we3 = We[192 + lane];
  float bev = be[0];
  for (int rr = 0; rr < 16; ++rr) {
    int gr = row0 + w * 16 + rr;
    if (gr >= nN) break;  // wave-uniform
    const float* rowp = nf + (size_t)gr * 128;
    float a0 = rowp[lane], a1 = rowp[64 + lane];
    float pdv = a0 * we0 + a1 * we1;
    float psv = a0 * we2 + a1 * we3;
#pragma unroll
    for (int o = 32; o; o >>= 1) {
      pdv += __shfl_xor(pdv, o);
      psv += __shfl_xor(psv, o);
    }
    if (lane == 0) {
      pd[gr] = pdv + bev;  // bias folded (added once per edge)
      ps[gr] = psv;
    }
  }
  // MFMA: wave w owns rows w*16..w*16+15, 8 col-tiles of 16, K=128 (4 ksteps)
  f32x4 acc[8];
#pragma unroll
  for (int c = 0; c < 8; ++c) acc[c] = (f32x4){0.f, 0.f, 0.f, 0.f};
  int rl = w * 16 + (lane & 15);
  const char* abase = reinterpret_cast<const char*>(Atile) + rl * 256;
  int ksel = (lane >> 4) * 16;
#pragma unroll
  for (int kstep = 0; kstep < 4; ++kstep) {
    int kb = kstep * 64 + ksel;
    bf16x8 afrag = *reinterpret_cast<const bf16x8*>(abase + (kb ^ ((rl & 7) << 4)));
#pragma unroll
    for (int ct = 0; ct < 8; ++ct) {
      bf16x8 bfrag = *reinterpret_cast<const bf16x8*>(wsw + ((size_t)((kstep * 8 + ct) * 64 + lane)) * 8);
      acc[ct] = __builtin_amdgcn_mfma_f32_16x16x32_bf16(afrag, bfrag, acc[ct], 0, 0, 0);
    }
  }
  // epilogue: D layout col=lane&15, row=(lane>>4)*4+reg; pack (c, c+1) via shfl
  int colbase = lane & 15;
  int rbase = row0 + w * 16 + ((lane >> 4) << 2);
#pragma unroll
  for (int ct = 0; ct < 8; ++ct) {
    int col = ct * 16 + colbase;
    float bb = bn[col];
#pragma unroll
    for (int r = 0; r < 4; ++r) {
      float x = acc[ct][r] + bb;
      x = x > 0.f ? x : 0.01f * x;
      float y = __shfl_xor(x, 1);
      int gr = rbase + r;
      if (!(lane & 1) && gr < nN)
        hv2[(size_t)gr * 64 + ct * 8 + (colbase >> 1)] = pack_bf16(x, y);
    }
  }
}

// ---------------- phase 1: multisplit bin by dst>>6 into fixed-CAP slots ----------------
__global__ __launch_bounds__(256) void bin_kernel(
    const int* __restrict__ src, const int* __restrict__ dst,
    int* __restrict__ bcnt, unsigned* __restrict__ inter, int nE, int nB) {
  __shared__ int cnt[1024];  // supports nN <= 65536
  int t = threadIdx.x;
  for (int b = t; b < nB; b += 256) cnt[b] = 0;
  __syncthreads();
  int base = blockIdx.x * BIN_CHUNK;
  int dv[16];
#pragma unroll
  for (int k = 0; k < 16; ++k) {
    int e = base + t + k * 256;
    dv[k] = (e < nE) ? dst[e] : -1;
    if (dv[k] >= 0) atomicAdd(&cnt[dv[k] >> BK_SHIFT], 1);
  }
  __syncthreads();
  // reserve global bucket ranges; counter slot becomes this wg's running base
  for (int b = t; b < nB; b += 256) {
    int c = cnt[b];
    cnt[b] = c ? atomicAdd(&bcnt[b], c) : 0;
  }
  __syncthreads();
#pragma unroll
  for (int k = 0; k < 16; ++k) {
    int e = base + t + k * 256;
    if (e < nE) {
      int d = dv[k];
      int b = d >> BK_SHIFT;
      int pos = atomicAdd(&cnt[b], 1);
      if (pos < BK_CAP)
        inter[(size_t)b * BK_CAP + pos] = ((unsigned)src[e] << BK_SHIFT) | (unsigned)(d & 63);
    }
  }
}

// ---------------- phase 2: per-bucket LDS sort -> ssorted + offs/deg ----------------
__global__ __launch_bounds__(256) void place_kernel(
    const int* __restrict__ bcnt, const unsigned* __restrict__ inter,
    ushort* __restrict__ ssorted, int* __restrict__ offs, int* __restrict__ degv, int nN) {
  __shared__ unsigned recs[BK_CAP];
  __shared__ ushort stage[BK_CAP];
  __shared__ int cnt[64], cur[64];
  int b = blockIdx.x;
  int t = threadIdx.x;
  int cntE = min(bcnt[b], BK_CAP);
  for (int i = t; i < cntE; i += 256) recs[i] = inter[(size_t)b * BK_CAP + i];
  if (t < 64) cnt[t] = 0;
  __syncthreads();
  for (int i = t; i < cntE; i += 256) atomicAdd(&cnt[recs[i] & 63], 1);
  __syncthreads();
  if (t < 64) {  // wave-0 exclusive scan of the 64 per-dst counts
    int c = cnt[t];
    int incl = c;
#pragma unroll
    for (int o = 1; o < 64; o <<= 1) {
      int x = __shfl_up(incl, o);
      if (t >= o) incl += x;
    }
    int excl = incl - c;
    cur[t] = excl;
    int node = b * 64 + t;
    if (node < nN) {
      offs[node] = b * BK_CAP + excl;
      degv[node] = c;
    }
  }
  __syncthreads();
  for (int i = t; i < cntE; i += 256) {
    unsigned r = recs[i];
    int pos = atomicAdd(&cur[r & 63], 1);
    stage[pos] = (ushort)(r >> BK_SHIFT);
  }
  __syncthreads();
  for (int i = t; i < cntE; i += 256) ssorted[(size_t)b * BK_CAP + i] = stage[i];
}

// ---------------- per-node softmax + weighted aggregation ----------------
// one wave per destination node; lane handles feature pair (2*lane, 2*lane+1).
// Fast path (deg<=64): edge list in registers, 16 gathers in flight; weights
// computed (shuffles only) while the gathers are outstanding.
__global__ __launch_bounds__(256) void aggregate_kernel(
    const int* __restrict__ offs, const int* __restrict__ degv,
    const ushort* __restrict__ ssorted, const float* __restrict__ pd,
    const float* __restrict__ ps, const unsigned* __restrict__ hv2,
    float* __restrict__ out, int nN) {
  int v = blockIdx.x * 4 + (threadIdx.x >> 6);
  if (v >= nN) return;
  int lane = threadIdx.x & 63;
  int s0 = offs[v];
  int deg = degv[v];
  float2* out2 = reinterpret_cast<float2*>(out) + (size_t)v * 64 + lane;
  if (deg == 0) {  // no incoming edges: c = 0 -> elu(0) = 0
    *out2 = make_float2(0.f, 0.f);
    return;
  }
  float pdv = pd[v];
  float acc0 = 0.f, acc1 = 0.f;
  if (deg <= 64) {
    // one edge per lane; logit recomputed from L2-resident ps
    int se = ssorted[s0 + (lane < deg ? lane : 0)];
    float xe = pdv + ps[se];
    xe = xe > 0.f ? xe : 0.01f * xe;
    float m = lane < deg ? xe : -1e30f;
#pragma unroll
    for (int o = 32; o; o >>= 1) m = fmaxf(m, __shfl_xor(m, o));
    float ex = lane < deg ? __expf(xe - m) : 0.f;
    float ssum = ex;
#pragma unroll
    for (int o = 32; o; o >>= 1) ssum += __shfl_xor(ssum, o);
    float exn = ex * (1.f / ssum);  // pre-normalized weight (ssum >= 1)
    for (int i0 = 0; i0 < deg; i0 += 16) {
      int u[16];
#pragma unroll
      for (int j = 0; j < 16; ++j) {
        int jj = i0 + j;
        u[j] = __shfl(se, jj < deg ? jj : deg - 1);
      }
      unsigned pk[16];
#pragma unroll
      for (int j = 0; j < 16; ++j) pk[j] = hv2[(u[j] << 6) + lane];  // 16 in flight
      float aw[16];
#pragma unroll
      for (int j = 0; j < 16; ++j) {  // shuffles only — overlaps the loads
        int jj = i0 + j;
        float exj = __shfl(exn, jj < deg ? jj : 0);
        aw[j] = jj < deg ? exj : 0.f;
      }
#pragma unroll
      for (int j = 0; j < 16; ++j) {
        acc0 += aw[j] * __uint_as_float(pk[j] << 16);
        acc1 += aw[j] * __uint_as_float(pk[j] & 0xffff0000u);
      }
    }
  } else {
    // rare fallback: 3-pass over global edge list
    float m = -1e30f;
    for (int i = s0 + lane; i < s0 + deg; i += 64) {
      float x = pdv + ps[ssorted[i]];
      x = x > 0.f ? x : 0.01f * x;
      m = fmaxf(m, x);
    }
#pragma unroll
    for (int o = 32; o; o >>= 1) m = fmaxf(m, __shfl_xor(m, o));
    float ssum = 0.f;
    for (int i = s0 + lane; i < s0 + deg; i += 64) {
      float x = pdv + ps[ssorted[i]];
      x = x > 0.f ? x : 0.01f * x;
      ssum += __expf(x - m);
    }
#pragma unroll
    for (int o = 32; o; o >>= 1) ssum += __shfl_xor(ssum, o);
    float rinv = 1.f / ssum;
    for (int i0 = s0; i0 < s0 + deg; i0 += 8) {
      int u[8];
      float aw[8];
      unsigned pk[8];
#pragma unroll
      for (int j = 0; j < 8; ++j) {
        int idx = i0 + j;
        bool ok = idx < s0 + deg;
        int s = ssorted[ok ? idx : s0];
        u[j] = s;
        float x = pdv + ps[s];
        x = x > 0.f ? x : 0.01f * x;
        aw[j] = ok ? __expf(x - m) * rinv : 0.f;
      }
#pragma unroll
      for (int j = 0; j < 8; ++j) pk[j] = hv2[(u[j] << 6) + lane];
#pragma unroll
      for (int j = 0; j < 8; ++j) {
        acc0 += aw[j] * __uint_as_float(pk[j] << 16);
        acc1 += aw[j] * __uint_as_float(pk[j] & 0xffff0000u);
      }
    }
  }
  float e0 = acc0 > 0.f ? acc0 : expm1f(acc0);
  float e1v = acc1 > 0.f ? acc1 : expm1f(acc1);
  *out2 = make_float2(e0, e1v);
}

extern "C" void kernel_launch(void* const* d_in, const int* in_sizes, int n_in,
                              void* d_out, int out_size, void* d_ws, size_t ws_size,
                              hipStream_t stream) {
  const float* nf = (const float*)d_in[0];
  const int* src = (const int*)d_in[1];
  const int* dst = (const int*)d_in[2];
  const float* We = (const float*)d_in[3];
  const float* be = (const float*)d_in[4];
  const float* Wn = (const float*)d_in[5];
  const float* bn = (const float*)d_in[6];
  float* out = (float*)d_out;
  int nN = in_sizes[0] / 128;
  int nE = in_sizes[1];
  int nB = (nN + 63) >> BK_SHIFT;

  // workspace carve (~23 MB), 16B-aligned chunks first
  char* wsp = (char*)d_ws;
  unsigned* hv2 = (unsigned*)wsp;   wsp += (size_t)nN * 64 * 4;
  unsigned* inter = (unsigned*)wsp; wsp += (size_t)nB * BK_CAP * 4;
  ushort* wsw = (ushort*)wsp;       wsp += 16384 * 2;
  float* pd = (float*)wsp;          wsp += (size_t)nN * 4;
  float* ps = (float*)wsp;          wsp += (size_t)nN * 4;
  int* offs = (int*)wsp;            wsp += (size_t)nN * 4;
  int* degv = (int*)wsp;            wsp += (size_t)nN * 4;
  int* bcnt = (int*)wsp;            wsp += (size_t)nB * 4;
  ushort* ssorted = (ushort*)wsp;   wsp += (size_t)nB * BK_CAP * 2;

  // wconv also zeroes bcnt (stream-ordered before bin_kernel).
  wconv_kernel<<<64, 256, 0, stream>>>(Wn, wsw, bcnt, nB);
  hv_mfma_kernel<<<(nN + 63) / 64, 256, 0, stream>>>(nf, wsw, bn, We, be, hv2, pd, ps, nN);
  bin_kernel<<<(nE + BIN_CHUNK - 1) / BIN_CHUNK, 256, 0, stream>>>(src, dst, bcnt, inter, nE, nB);
  place_kernel<<<nB, 256, 0, stream>>>(bcnt, inter, ssorted, offs, degv, nN);
  aggregate_kernel<<<(nN + 3) / 4, 256, 0, stream>>>(offs, degv, ssorted, pd, ps, hv2, out, nN);
}

// Round 8
// 87.345 us; speedup vs baseline: 1.1547x; 1.1547x over previous
//
#include <hip/hip_runtime.h>
#include <hip/hip_bf16.h>
#include <math.h>

// Problem: N=50000 nodes, E=800000 edges, D=G=128.
// out[v,:] = elu( sum_{e: dst(e)=v} softmax_e(leaky(pd[dst]+ps[src]+b)) * hv[src(e),:] )
// pd[v] = nf[v]·W_edge[0:D] (+ b_edge), ps[v] = nf[v]·W_edge[D:2D]
// hv = leaky_relu(nf @ W_node + b_node) via bf16 MFMA, stored as packed bf16 pairs.
// Edge ordering via 2-level binned multisplit (64-dst buckets, fixed CAP slots);
// requires nN <= 65536 (src/dst packed in 16 bits) — holds for this problem.

#define BK_SHIFT 6
#define BK_CAP 2048
#define BIN_CHUNK 4096

using bf16x8 = __attribute__((ext_vector_type(8))) __bf16;
using f32x4 = __attribute__((ext_vector_type(4))) float;

static __device__ __forceinline__ unsigned pack_bf16(float x0, float x1) {
  unsigned u0 = (unsigned)__bfloat16_as_ushort(__float2bfloat16(x0));
  unsigned u1 = (unsigned)__bfloat16_as_ushort(__float2bfloat16(x1));
  return u0 | (u1 << 16);
}

// ---- one-time: convert Wn (128x128 f32) to bf16, pre-swizzled into B-fragment order.
// Also zeroes bcnt (replaces hipMemsetAsync — saves one in-graph fill dispatch).
__global__ void wconv_kernel(const float* __restrict__ Wn, ushort* __restrict__ wsw,
                             int* __restrict__ bcnt, int nB) {
  int i = blockIdx.x * 256 + threadIdx.x;  // 0..16383
  if (i < nB) bcnt[i] = 0;
  int j = i & 7, l = (i >> 3) & 63, ct = (i >> 9) & 7, kstep = i >> 12;
  int k = kstep * 32 + ((l >> 4) << 3) + j;
  int c = ct * 16 + (l & 15);
  wsw[i] = __bfloat16_as_ushort(__float2bfloat16(Wn[k * 128 + c]));
}

// ---------------- fused: hv MFMA GEMM (bf16) + per-node edge scalars ----------------
__global__ __launch_bounds__(256) void hv_mfma_kernel(
    const float* __restrict__ nf, const ushort* __restrict__ wsw,
    const float* __restrict__ bn, const float* __restrict__ We,
    const float* __restrict__ be, unsigned* __restrict__ hv2,
    float* __restrict__ pd, float* __restrict__ ps, int nN) {
  __shared__ unsigned Atile[64 * 64];  // 64 rows x 256B of bf16, XOR-swizzled 16B slots
  int row0 = blockIdx.x * 64;
  int t = threadIdx.x;
#pragma unroll
  for (int ss = 0; ss < 4; ++ss) {
    int s = t + ss * 256;
    int r = s >> 4, sl = s & 15;
    int gr = row0 + r;
    float4 f0 = make_float4(0.f, 0.f, 0.f, 0.f), f1 = f0;
    if (gr < nN) {
      const float4* p = reinterpret_cast<const float4*>(nf + (size_t)gr * 128 + sl * 8);
      f0 = p[0];
      f1 = p[1];
    }
    uint4 pk;
    pk.x = pack_bf16(f0.x, f0.y);
    pk.y = pack_bf16(f0.z, f0.w);
    pk.z = pack_bf16(f1.x, f1.y);
    pk.w = pack_bf16(f1.z, f1.w);
    int byte = r * 256 + ((sl * 16) ^ ((r & 7) << 4));  // T2 swizzle vs 16-way conflict
    *reinterpret_cast<uint4*>(reinterpret_cast<char*>(Atile) + byte) = pk;
  }
  __syncthreads();
  int lane = t & 63, w = t >> 6;
  // edge-projection scalars (fp32, reads nf from global -> L1/L2-hot after staging)
  float we0 = We[lane], we1 = We[64 + lane], we2 = We[128 + lane], we3 = We[192 + lane];
  float bev = be[0];
  for (int rr = 0; rr < 16; ++rr) {
    int gr = row0 + w * 16 + rr;
    if (gr >= nN) break;  // wave-uniform
    const float* rowp = nf + (size_t)gr * 128;
    float a0 = rowp[lane], a1 = rowp[64 + lane];
    float pdv = a0 * we0 + a1 * we1;
    float psv = a0 * we2 + a1 * we3;
#pragma unroll
    for (int o = 32; o; o >>= 1) {
      pdv += __shfl_xor(pdv, o);
      psv += __shfl_xor(psv, o);
    }
    if (lane == 0) {
      pd[gr] = pdv + bev;  // bias folded (added once per edge)
      ps[gr] = psv;
    }
  }
  // MFMA: wave w owns rows w*16..w*16+15, 8 col-tiles of 16, K=128 (4 ksteps)
  f32x4 acc[8];
#pragma unroll
  for (int c = 0; c < 8; ++c) acc[c] = (f32x4){0.f, 0.f, 0.f, 0.f};
  int rl = w * 16 + (lane & 15);
  const char* abase = reinterpret_cast<const char*>(Atile) + rl * 256;
  int ksel = (lane >> 4) * 16;
#pragma unroll
  for (int kstep = 0; kstep < 4; ++kstep) {
    int kb = kstep * 64 + ksel;
    bf16x8 afrag = *reinterpret_cast<const bf16x8*>(abase + (kb ^ ((rl & 7) << 4)));
#pragma unroll
    for (int ct = 0; ct < 8; ++ct) {
      bf16x8 bfrag = *reinterpret_cast<const bf16x8*>(wsw + ((size_t)((kstep * 8 + ct) * 64 + lane)) * 8);
      acc[ct] = __builtin_amdgcn_mfma_f32_16x16x32_bf16(afrag, bfrag, acc[ct], 0, 0, 0);
    }
  }
  // epilogue: D layout col=lane&15, row=(lane>>4)*4+reg; pack (c, c+1) via shfl
  int colbase = lane & 15;
  int rbase = row0 + w * 16 + ((lane >> 4) << 2);
#pragma unroll
  for (int ct = 0; ct < 8; ++ct) {
    int col = ct * 16 + colbase;
    float bb = bn[col];
#pragma unroll
    for (int r = 0; r < 4; ++r) {
      float x = acc[ct][r] + bb;
      x = x > 0.f ? x : 0.01f * x;
      float y = __shfl_xor(x, 1);
      int gr = rbase + r;
      if (!(lane & 1) && gr < nN)
        hv2[(size_t)gr * 64 + ct * 8 + (colbase >> 1)] = pack_bf16(x, y);
    }
  }
}

// ---------------- phase 1: multisplit bin by dst>>6 into fixed-CAP slots ----------------
__global__ __launch_bounds__(256) void bin_kernel(
    const int* __restrict__ src, const int* __restrict__ dst,
    int* __restrict__ bcnt, unsigned* __restrict__ inter, int nE, int nB) {
  __shared__ int cnt[1024];  // supports nN <= 65536
  int t = threadIdx.x;
  for (int b = t; b < nB; b += 256) cnt[b] = 0;
  __syncthreads();
  int base = blockIdx.x * BIN_CHUNK;
  int dv[16];
#pragma unroll
  for (int k = 0; k < 16; ++k) {
    int e = base + t + k * 256;
    dv[k] = (e < nE) ? dst[e] : -1;
    if (dv[k] >= 0) atomicAdd(&cnt[dv[k] >> BK_SHIFT], 1);
  }
  __syncthreads();
  // reserve global bucket ranges; counter slot becomes this wg's running base
  for (int b = t; b < nB; b += 256) {
    int c = cnt[b];
    cnt[b] = c ? atomicAdd(&bcnt[b], c) : 0;
  }
  __syncthreads();
#pragma unroll
  for (int k = 0; k < 16; ++k) {
    int e = base + t + k * 256;
    if (e < nE) {
      int d = dv[k];
      int b = d >> BK_SHIFT;
      int pos = atomicAdd(&cnt[b], 1);
      if (pos < BK_CAP)
        inter[(size_t)b * BK_CAP + pos] = ((unsigned)src[e] << BK_SHIFT) | (unsigned)(d & 63);
    }
  }
}

// ---------------- phase 2: per-bucket LDS sort -> ssorted + offs/deg ----------------
__global__ __launch_bounds__(256) void place_kernel(
    const int* __restrict__ bcnt, const unsigned* __restrict__ inter,
    ushort* __restrict__ ssorted, int* __restrict__ offs, int* __restrict__ degv, int nN) {
  __shared__ unsigned recs[BK_CAP];
  __shared__ ushort stage[BK_CAP];
  __shared__ int cnt[64], cur[64];
  int b = blockIdx.x;
  int t = threadIdx.x;
  int cntE = min(bcnt[b], BK_CAP);
  for (int i = t; i < cntE; i += 256) recs[i] = inter[(size_t)b * BK_CAP + i];
  if (t < 64) cnt[t] = 0;
  __syncthreads();
  for (int i = t; i < cntE; i += 256) atomicAdd(&cnt[recs[i] & 63], 1);
  __syncthreads();
  if (t < 64) {  // wave-0 exclusive scan of the 64 per-dst counts
    int c = cnt[t];
    int incl = c;
#pragma unroll
    for (int o = 1; o < 64; o <<= 1) {
      int x = __shfl_up(incl, o);
      if (t >= o) incl += x;
    }
    int excl = incl - c;
    cur[t] = excl;
    int node = b * 64 + t;
    if (node < nN) {
      offs[node] = b * BK_CAP + excl;
      degv[node] = c;
    }
  }
  __syncthreads();
  for (int i = t; i < cntE; i += 256) {
    unsigned r = recs[i];
    int pos = atomicAdd(&cur[r & 63], 1);
    stage[pos] = (ushort)(r >> BK_SHIFT);
  }
  __syncthreads();
  for (int i = t; i < cntE; i += 256) ssorted[(size_t)b * BK_CAP + i] = stage[i];
}

// ---------------- per-node softmax + weighted aggregation ----------------
// one wave per destination node. Softmax: one edge per lane (deg<=64 fast path).
// Gather: 4 edges per wave — 16-lane group per edge, 8 features (uint4) per lane;
// edge-overhead instructions (bpermute, selects, addressing) amortize over 4 edges.
__global__ __launch_bounds__(256) void aggregate_kernel(
    const int* __restrict__ offs, const int* __restrict__ degv,
    const ushort* __restrict__ ssorted, const float* __restrict__ pd,
    const float* __restrict__ ps, const unsigned* __restrict__ hv2,
    float* __restrict__ out, int nN) {
  int v = blockIdx.x * 4 + (threadIdx.x >> 6);
  if (v >= nN) return;
  int lane = threadIdx.x & 63;
  if (degv[v] == 0) {  // no incoming edges: c = 0 -> elu(0) = 0
    reinterpret_cast<float2*>(out)[(size_t)v * 64 + lane] = make_float2(0.f, 0.f);
    return;
  }
  int s0 = offs[v];
  int deg = degv[v];
  float pdv = pd[v];
  if (deg <= 64) {
    // softmax: one edge per lane
    int se = ssorted[s0 + (lane < deg ? lane : 0)];
    float xe = pdv + ps[se];
    xe = xe > 0.f ? xe : 0.01f * xe;
    float m = lane < deg ? xe : -1e30f;
#pragma unroll
    for (int o = 32; o; o >>= 1) m = fmaxf(m, __shfl_xor(m, o));
    float ex = lane < deg ? __expf(xe - m) : 0.f;
    float ssum = ex;
#pragma unroll
    for (int o = 32; o; o >>= 1) ssum += __shfl_xor(ssum, o);
    float exn = ex * (1.f / ssum);  // pre-normalized weight (ssum >= 1)
    // gather: 4 edges/wave, lane group g=lane>>4 takes edge i0+4j+g,
    // lane handles features 8*(lane&15) .. +7 (uint4 = 16B)
    int g = lane >> 4, fl = lane & 15;
    float a0 = 0.f, a1 = 0.f, a2 = 0.f, a3 = 0.f, a4 = 0.f, a5 = 0.f, a6 = 0.f, a7 = 0.f;
    for (int i0 = 0; i0 < deg; i0 += 16) {
      int u[4];
      uint4 pk[4];
      float aw[4];
#pragma unroll
      for (int j = 0; j < 4; ++j) {
        int e = i0 + 4 * j + g;
        u[j] = __shfl(se, e < deg ? e : 0);
      }
#pragma unroll
      for (int j = 0; j < 4; ++j)
        pk[j] = *reinterpret_cast<const uint4*>(hv2 + (u[j] << 6) + fl * 4);  // 4 in flight
#pragma unroll
      for (int j = 0; j < 4; ++j) {  // shuffles while loads are in flight
        int e = i0 + 4 * j + g;
        float exj = __shfl(exn, e < deg ? e : 0);
        aw[j] = e < deg ? exj : 0.f;
      }
#pragma unroll
      for (int j = 0; j < 4; ++j) {
        a0 += aw[j] * __uint_as_float(pk[j].x << 16);
        a1 += aw[j] * __uint_as_float(pk[j].x & 0xffff0000u);
        a2 += aw[j] * __uint_as_float(pk[j].y << 16);
        a3 += aw[j] * __uint_as_float(pk[j].y & 0xffff0000u);
        a4 += aw[j] * __uint_as_float(pk[j].z << 16);
        a5 += aw[j] * __uint_as_float(pk[j].z & 0xffff0000u);
        a6 += aw[j] * __uint_as_float(pk[j].w << 16);
        a7 += aw[j] * __uint_as_float(pk[j].w & 0xffff0000u);
      }
    }
    // combine the 4 edge-groups (xor 16, then xor 32)
#pragma unroll
    for (int o = 16; o <= 32; o <<= 1) {
      a0 += __shfl_xor(a0, o);
      a1 += __shfl_xor(a1, o);
      a2 += __shfl_xor(a2, o);
      a3 += __shfl_xor(a3, o);
      a4 += __shfl_xor(a4, o);
      a5 += __shfl_xor(a5, o);
      a6 += __shfl_xor(a6, o);
      a7 += __shfl_xor(a7, o);
    }
    if (g == 0) {  // lanes 0-15 write 2 float4s each (512B total, coalesced)
      float4 r0, r1;
      r0.x = a0 > 0.f ? a0 : expm1f(a0);
      r0.y = a1 > 0.f ? a1 : expm1f(a1);
      r0.z = a2 > 0.f ? a2 : expm1f(a2);
      r0.w = a3 > 0.f ? a3 : expm1f(a3);
      r1.x = a4 > 0.f ? a4 : expm1f(a4);
      r1.y = a5 > 0.f ? a5 : expm1f(a5);
      r1.z = a6 > 0.f ? a6 : expm1f(a6);
      r1.w = a7 > 0.f ? a7 : expm1f(a7);
      float4* op = reinterpret_cast<float4*>(out + (size_t)v * 128 + fl * 8);
      op[0] = r0;
      op[1] = r1;
    }
  } else {
    // rare fallback: 3-pass over global edge list, 2 features per lane
    float acc0 = 0.f, acc1 = 0.f;
    float m = -1e30f;
    for (int i = s0 + lane; i < s0 + deg; i += 64) {
      float x = pdv + ps[ssorted[i]];
      x = x > 0.f ? x : 0.01f * x;
      m = fmaxf(m, x);
    }
#pragma unroll
    for (int o = 32; o; o >>= 1) m = fmaxf(m, __shfl_xor(m, o));
    float ssum = 0.f;
    for (int i = s0 + lane; i < s0 + deg; i += 64) {
      float x = pdv + ps[ssorted[i]];
      x = x > 0.f ? x : 0.01f * x;
      ssum += __expf(x - m);
    }
#pragma unroll
    for (int o = 32; o; o >>= 1) ssum += __shfl_xor(ssum, o);
    float rinv = 1.f / ssum;
    for (int i0 = s0; i0 < s0 + deg; i0 += 8) {
      int u[8];
      float aw[8];
      unsigned pk[8];
#pragma unroll
      for (int j = 0; j < 8; ++j) {
        int idx = i0 + j;
        bool ok = idx < s0 + deg;
        int s = ssorted[ok ? idx : s0];
        u[j] = s;
        float x = pdv + ps[s];
        x = x > 0.f ? x : 0.01f * x;
        aw[j] = ok ? __expf(x - m) * rinv : 0.f;
      }
#pragma unroll
      for (int j = 0; j < 8; ++j) pk[j] = hv2[(u[j] << 6) + lane];
#pragma unroll
      for (int j = 0; j < 8; ++j) {
        acc0 += aw[j] * __uint_as_float(pk[j] << 16);
        acc1 += aw[j] * __uint_as_float(pk[j] & 0xffff0000u);
      }
    }
    float e0 = acc0 > 0.f ? acc0 : expm1f(acc0);
    float e1v = acc1 > 0.f ? acc1 : expm1f(acc1);
    reinterpret_cast<float2*>(out)[(size_t)v * 64 + lane] = make_float2(e0, e1v);
  }
}

extern "C" void kernel_launch(void* const* d_in, const int* in_sizes, int n_in,
                              void* d_out, int out_size, void* d_ws, size_t ws_size,
                              hipStream_t stream) {
  const float* nf = (const float*)d_in[0];
  const int* src = (const int*)d_in[1];
  const int* dst = (const int*)d_in[2];
  const float* We = (const float*)d_in[3];
  const float* be = (const float*)d_in[4];
  const float* Wn = (const float*)d_in[5];
  const float* bn = (const float*)d_in[6];
  float* out = (float*)d_out;
  int nN = in_sizes[0] / 128;
  int nE = in_sizes[1];
  int nB = (nN + 63) >> BK_SHIFT;

  // workspace carve (~23 MB), 16B-aligned chunks first
  char* wsp = (char*)d_ws;
  unsigned* hv2 = (unsigned*)wsp;   wsp += (size_t)nN * 64 * 4;
  unsigned* inter = (unsigned*)wsp; wsp += (size_t)nB * BK_CAP * 4;
  ushort* wsw = (ushort*)wsp;       wsp += 16384 * 2;
  float* pd = (float*)wsp;          wsp += (size_t)nN * 4;
  float* ps = (float*)wsp;          wsp += (size_t)nN * 4;
  int* offs = (int*)wsp;            wsp += (size_t)nN * 4;
  int* degv = (int*)wsp;            wsp += (size_t)nN * 4;
  int* bcnt = (int*)wsp;            wsp += (size_t)nB * 4;
  ushort* ssorted = (ushort*)wsp;   wsp += (size_t)nB * BK_CAP * 2;

  // wconv also zeroes bcnt (stream-ordered before bin_kernel).
  wconv_kernel<<<64, 256, 0, stream>>>(Wn, wsw, bcnt, nB);
  hv_mfma_kernel<<<(nN + 63) / 64, 256, 0, stream>>>(nf, wsw, bn, We, be, hv2, pd, ps, nN);
  bin_kernel<<<(nE + BIN_CHUNK - 1) / BIN_CHUNK, 256, 0, stream>>>(src, dst, bcnt, inter, nE, nB);
  place_kernel<<<nB, 256, 0, stream>>>(bcnt, inter, ssorted, offs, degv, nN);
  aggregate_kernel<<<(nN + 3) / 4, 256, 0, stream>>>(offs, degv, ssorted, pd, ps, hv2, out, nN);
}